// Round 6
// baseline (504.619 us; speedup 1.0000x reference)
//
#include <hip/hip_runtime.h>
#include <hip/hip_bf16.h>
#include <stdint.h>

// KAN layer = one augmented GEMM:
//   out[4096,1024] = [silu(x) | rbf_basis(x)] @ [W_base ; W_spline]
//   M=4096, N=1024, K=1024+20480=21504, 1.8e11 FLOP -> bf16 MFMA.
// Pipeline (all stream-ordered):
//   1. prep_silu:  A1 = silu(x) bf16             [4096][1024]
//   2. prep_wt:    W1t = W_base^T bf16 (N-major)  [1024][1024]
//   3. gemm (K=1024, grid 256): out = A1 @ W1t^T
//   for pass p in 0..npass-1 (CI = 1024/npass input columns each):
//   4. prep_basis: A2 = exp(-((x-mu)/s)^2) bf16  [4096][CI*20]
//   5. prep_wt:    W2t = W_spline^T bf16         [1024][CI*20]
//   6. gemm (K z-split in 2, grid 512): Cp = z0 part; out += z1 part
//   7. add: out += Cp
// npass chosen from ws_size (2 -> 132 MB ... 16 -> 40 MB), deterministic.

typedef short short8 __attribute__((ext_vector_type(8)));
typedef __bf16 bf16x8 __attribute__((ext_vector_type(8)));
typedef float f32x4 __attribute__((ext_vector_type(4)));
typedef unsigned int u32;

__device__ __forceinline__ unsigned short f2bf(float f) {
  __hip_bfloat16 h = __float2bfloat16(f);
  return __builtin_bit_cast(unsigned short, h);
}

__device__ __forceinline__ void gload_lds16(const unsigned short* g, unsigned short* l) {
  // async global->LDS, 16B per lane; LDS dest = wave-uniform base + lane*16
  __builtin_amdgcn_global_load_lds(
      (const __attribute__((address_space(1))) u32*)(const void*)g,
      (__attribute__((address_space(3))) u32*)(void*)l, 16, 0, 0);
}

// ---------------- prep kernels ----------------

// silu(x) -> bf16, 8 elems/thread. grid 2048x256 exact (4096*1024/8).
__global__ void prep_silu(const float* __restrict__ x, unsigned short* __restrict__ A1) {
  int g = blockIdx.x * 256 + threadIdx.x;
  const float4* x4 = reinterpret_cast<const float4*>(x);
  float4 a = x4[g * 2], b = x4[g * 2 + 1];
  float v[8] = {a.x, a.y, a.z, a.w, b.x, b.y, b.z, b.w};
  union { unsigned short u[8]; short8 v8; } o;
#pragma unroll
  for (int j = 0; j < 8; ++j) {
    float s = v[j] / (1.f + __expf(-v[j]));
    o.u[j] = f2bf(s);
  }
  *reinterpret_cast<short8*>(&A1[(size_t)g * 8]) = o.v8;
}

// RBF basis for i in [i0, i0+CI): A2[b][(i-i0)*20+g] = exp(-d^2),
// d = (x+2)*4.75 - g  (SIGMA = 4/19 -> 1/SIGMA = 4.75 exactly).
// Row length L = CI*20; 8 elems/thread; grid covers 4096*L/8 threads exactly.
__global__ void prep_basis(const float* __restrict__ x, unsigned short* __restrict__ A2,
                           int i0, int L) {
  int g = blockIdx.x * 256 + threadIdx.x;
  int e0 = g * 8;
  int b = e0 / L;
  int k0 = e0 - b * L;
  const float* xr = x + (size_t)b * 1024 + i0;
  union { unsigned short u[8]; short8 v8; } o;
#pragma unroll
  for (int j = 0; j < 8; ++j) {
    int k = k0 + j;
    int il = (int)(((unsigned)k * 104858u) >> 21);  // k/20, exact for k < 262144
    int gg = k - il * 20;
    float xv = xr[il];
    float d = (xv + 2.0f) * 4.75f - (float)gg;
    o.u[j] = f2bf(__expf(-d * d));
  }
  *reinterpret_cast<short8*>(&A2[(size_t)b * L + k0]) = o.v8;
}

// W [Kp][1024] fp32 -> Bt [1024][Kp] bf16 (transpose+cast), 64x64 LDS tiles.
// grid = (Kp/64) * 16 blocks x 256 thr.
__global__ void prep_wt(const float* __restrict__ W, unsigned short* __restrict__ Bt, int Kp) {
  __shared__ unsigned short tile[64][72];
  int tiles_k = Kp >> 6;
  int bk = blockIdx.x % tiles_k, bn = blockIdx.x / tiles_k;
  int t = threadIdx.x;
  int lr = t >> 4;          // 0..15
  int lc = (t & 15) * 4;    // 0..60
#pragma unroll
  for (int r = 0; r < 4; ++r) {
    int row = r * 16 + lr;
    float4 v = *reinterpret_cast<const float4*>(&W[(size_t)(bk * 64 + row) * 1024 + bn * 64 + lc]);
    tile[row][lc + 0] = f2bf(v.x);
    tile[row][lc + 1] = f2bf(v.y);
    tile[row][lc + 2] = f2bf(v.z);
    tile[row][lc + 3] = f2bf(v.w);
  }
  __syncthreads();
  int nr = t >> 3;          // 0..31
  int kc = (t & 7) * 8;     // 0..56
#pragma unroll
  for (int r = 0; r < 2; ++r) {
    int n = r * 32 + nr;
    union { unsigned short u[8]; short8 v8; } o;
#pragma unroll
    for (int j = 0; j < 8; ++j) o.u[j] = tile[kc + j][n];
    *reinterpret_cast<short8*>(&Bt[(size_t)(bn * 64 + n) * Kp + bk * 64 + kc]) = o.v8;
  }
}

// out += part
__global__ void add_kernel(float* __restrict__ out, const float* __restrict__ part, int n4) {
  int i = blockIdx.x * 256 + threadIdx.x;
  int stride = gridDim.x * 256;
  for (; i < n4; i += stride) {
    float4 a = reinterpret_cast<float4*>(out)[i];
    float4 b = reinterpret_cast<const float4*>(part)[i];
    a.x += b.x; a.y += b.y; a.z += b.z; a.w += b.w;
    reinterpret_cast<float4*>(out)[i] = a;
  }
}

// ---------------- GEMM ----------------
// C[M,N] (+)= A[M,K] @ Bt[N,K]^T, bf16 inputs, fp32 out.
// 128x128x64 tile, 4 waves (each a 64x64 quadrant of 4x4 16x16 frags),
// mfma_f32_16x16x32_bf16, global_load_lds(16B) staging, single LDS buffer.
// SPLIT: grid = 512 = 2 z-slices x 256 tiles; z0 -> C0 (=), z1 -> C1 (+=).
template <bool SPLIT>
__global__ __launch_bounds__(256, 2) void gemm_bf16(
    const unsigned short* __restrict__ A, int lda,
    const unsigned short* __restrict__ Bt, int ldb,
    float* __restrict__ C0, float* __restrict__ C1, int Kz) {
  const int tid = threadIdx.x;
  const int wid = tid >> 6, lane = tid & 63;

  // XCD-aware swizzle (nwg % 8 == 0): each XCD gets a contiguous wg chunk
  const int cpx = gridDim.x >> 3;
  const int wg = (blockIdx.x & 7) * cpx + (blockIdx.x >> 3);
  const int mtile = wg & 31;
  const int ntile = (wg >> 5) & 7;
  const int z = SPLIT ? (wg >> 8) : 0;
  const int brow = mtile * 128, bcol = ntile * 128;
  const int kbase = z * Kz;

  __shared__ __align__(16) unsigned short As[128 * 64];
  __shared__ __align__(16) unsigned short Bs[128 * 64];

  // staging: 16 chunks of 1KB each for A and B; wave w owns chunks w*4..w*4+3
  const int srow = wid * 32 + (lane >> 3);  // + c*8
  const int scol = (lane & 7) * 8;
  const unsigned short* aptr = A + (size_t)(brow + srow) * lda + kbase + scol;
  const unsigned short* bptr = Bt + (size_t)(bcol + srow) * ldb + kbase + scol;
  unsigned short* lA = &As[wid * 2048];
  unsigned short* lB = &Bs[wid * 2048];

  const int wr = wid >> 1, wc = wid & 1;
  const int fr = lane & 15;
  const int fk = (lane >> 4) * 8;

  f32x4 acc[4][4] = {};

  for (int kt = 0; kt < Kz; kt += 64) {
#pragma unroll
    for (int c = 0; c < 4; ++c)
      gload_lds16(aptr + (size_t)(c * 8) * lda, lA + c * 512);
#pragma unroll
    for (int c = 0; c < 4; ++c)
      gload_lds16(bptr + (size_t)(c * 8) * ldb, lB + c * 512);
    aptr += 64;
    bptr += 64;
    __syncthreads();  // compiler drains vmcnt(0) before barrier -> tiles ready
#pragma unroll
    for (int ks = 0; ks < 2; ++ks) {
      bf16x8 af[4], bfr[4];
#pragma unroll
      for (int m = 0; m < 4; ++m)
        af[m] = __builtin_bit_cast(
            bf16x8, *reinterpret_cast<const short8*>(
                        &As[(wr * 64 + m * 16 + fr) * 64 + ks * 32 + fk]));
#pragma unroll
      for (int n = 0; n < 4; ++n)
        bfr[n] = __builtin_bit_cast(
            bf16x8, *reinterpret_cast<const short8*>(
                        &Bs[(wc * 64 + n * 16 + fr) * 64 + ks * 32 + fk]));
#pragma unroll
      for (int m = 0; m < 4; ++m)
#pragma unroll
        for (int n = 0; n < 4; ++n)
          acc[m][n] = __builtin_amdgcn_mfma_f32_16x16x32_bf16(af[m], bfr[n], acc[m][n], 0, 0, 0);
    }
    __syncthreads();  // all waves done reading before next stage overwrites
  }

  float* C = (SPLIT && z) ? C1 : C0;
  const bool accflag = SPLIT && (z == 1);
  // C/D layout (m89-verified): col = lane&15, row = (lane>>4)*4 + reg
  const int r0 = brow + wr * 64 + (lane >> 4) * 4;
  const int c0 = bcol + wc * 64 + (lane & 15);
#pragma unroll
  for (int m = 0; m < 4; ++m)
#pragma unroll
    for (int n = 0; n < 4; ++n)
#pragma unroll
      for (int j = 0; j < 4; ++j) {
        size_t idx = (size_t)(r0 + m * 16 + j) * 1024 + (c0 + n * 16);
        float v = acc[m][n][j];
        if (accflag)
          C[idx] += v;
        else
          C[idx] = v;
      }
}

// ---------------- launcher ----------------

extern "C" void kernel_launch(void* const* d_in, const int* in_sizes, int n_in,
                              void* d_out, int out_size, void* d_ws, size_t ws_size,
                              hipStream_t stream) {
  (void)in_sizes; (void)n_in; (void)out_size;
  const float* x = (const float*)d_in[0];
  const float* Wb = (const float*)d_in[1];
  const float* Ws = (const float*)d_in[2];
  // d_in[3] = mu, folded analytically (mu_g = -2 + g*(4/19))
  float* out = (float*)d_out;
  char* ws = (char*)d_ws;

  // fixed-region layout
  const size_t A1_off = 0;                       //  8,388,608 B
  const size_t W1t_off = 8388608;                //  2,097,152 B
  const size_t Cp_off = W1t_off + 2097152;       // 16,777,216 B
  const size_t dyn_off = Cp_off + 16777216;      // = 27,262,976
  unsigned short* A1  = (unsigned short*)(ws + A1_off);
  unsigned short* W1t = (unsigned short*)(ws + W1t_off);
  float*          Cp  = (float*)(ws + Cp_off);

  // pick npass (spline split) so dynamic buffers fit in ws:
  // per pass: A2 = 4096*CI*20*2 bytes, W2t = CI*20*1024*2 bytes, CI = 1024/npass
  int npass = 16;
  for (int np = 2; np <= 16; np <<= 1) {
    size_t CI = 1024 / np;
    size_t need = dyn_off + 4096ull * CI * 20 * 2 + CI * 20 * 1024 * 2;
    if (need <= ws_size) { npass = np; break; }
  }
  const int CI = 1024 / npass;
  const int Kp = CI * 20;          // K per pass (div by 64 for CI in {64..512})
  const int Kz = Kp / 2;           // per z-slice
  unsigned short* A2  = (unsigned short*)(ws + dyn_off);
  unsigned short* W2t = (unsigned short*)(ws + dyn_off + 4096ull * CI * 20 * 2);

  // base path
  prep_silu<<<2048, 256, 0, stream>>>(x, A1);
  prep_wt<<<256, 256, 0, stream>>>(Wb, W1t, 1024);
  gemm_bf16<false><<<256, 256, 0, stream>>>(A1, 1024, W1t, 1024, out, nullptr, 1024);

  // spline path: npass serial passes over input columns, each z-split in 2
  for (int p = 0; p < npass; ++p) {
    const int nb_basis = 4096 * Kp / 8 / 256;  // exact division
    prep_basis<<<nb_basis, 256, 0, stream>>>(x, A2, p * CI, Kp);
    prep_wt<<<(Kp / 64) * 16, 256, 0, stream>>>(Ws + (size_t)p * Kp * 1024, W2t, Kp);
    gemm_bf16<true><<<512, 256, 0, stream>>>(A2, Kp, W2t, Kp, Cp, out, Kz);
    add_kernel<<<2048, 256, 0, stream>>>(out, Cp, 1024 * 1024);
  }
}

// Round 7
// 474.922 us; speedup vs baseline: 1.0625x; 1.0625x over previous
//
#include <hip/hip_runtime.h>
#include <hip/hip_bf16.h>
#include <stdint.h>

// KAN layer = one augmented GEMM:
//   out[4096,1024] = [silu(x) | rbf_basis(x)] @ [W_base ; W_spline]
//   M=4096, N=1024, K=1024+20480=21504, 1.8e11 FLOP -> bf16 MFMA.
// R6 -> R7: occupancy fix. Spline GEMM z-split x4 (grid 1024 = 4 blocks/CU,
// was 2), partials merged with fp32 atomicAdd epilogue. Base GEMM plain-store
// initializes out; add_kernel + Cp buffer deleted.
// Pipeline:
//   1. prep_silu:  A1 = silu(x) bf16             [4096][1024]
//   2. prep_wt:    W1t = W_base^T bf16 (N-major)  [1024][1024]
//   3. gemm<false> (grid 256): out = A1 @ W1t^T   (plain store)
//   for pass p in 0..npass-1 (CI = 1024/npass input columns each):
//   4. prep_basis: A2 = exp(-((x-mu)/s)^2) bf16  [4096][CI*20]
//   5. prep_wt:    W2t = W_spline^T bf16         [1024][CI*20]
//   6. gemm<true> (grid 1024, 4 z-slices): out += partial (atomicAdd)
// npass chosen from ws_size (2 -> 115 MB ... 16 -> 38 MB), deterministic.

typedef short short8 __attribute__((ext_vector_type(8)));
typedef __bf16 bf16x8 __attribute__((ext_vector_type(8)));
typedef float f32x4 __attribute__((ext_vector_type(4)));
typedef unsigned int u32;

__device__ __forceinline__ unsigned short f2bf(float f) {
  __hip_bfloat16 h = __float2bfloat16(f);
  return __builtin_bit_cast(unsigned short, h);
}

__device__ __forceinline__ void gload_lds16(const unsigned short* g, unsigned short* l) {
  // async global->LDS, 16B per lane; LDS dest = wave-uniform base + lane*16
  __builtin_amdgcn_global_load_lds(
      (const __attribute__((address_space(1))) u32*)(const void*)g,
      (__attribute__((address_space(3))) u32*)(void*)l, 16, 0, 0);
}

// ---------------- prep kernels ----------------

// silu(x) -> bf16, 8 elems/thread. grid 2048x256 exact (4096*1024/8).
__global__ void prep_silu(const float* __restrict__ x, unsigned short* __restrict__ A1) {
  int g = blockIdx.x * 256 + threadIdx.x;
  const float4* x4 = reinterpret_cast<const float4*>(x);
  float4 a = x4[g * 2], b = x4[g * 2 + 1];
  float v[8] = {a.x, a.y, a.z, a.w, b.x, b.y, b.z, b.w};
  union { unsigned short u[8]; short8 v8; } o;
#pragma unroll
  for (int j = 0; j < 8; ++j) {
    float s = v[j] / (1.f + __expf(-v[j]));
    o.u[j] = f2bf(s);
  }
  *reinterpret_cast<short8*>(&A1[(size_t)g * 8]) = o.v8;
}

// RBF basis for i in [i0, i0+CI): A2[b][(i-i0)*20+g] = exp(-d^2),
// d = (x+2)*4.75 - g  (SIGMA = 4/19 -> 1/SIGMA = 4.75 exactly).
// Row length L = CI*20; 8 elems/thread; grid covers 4096*L/8 threads exactly.
__global__ void prep_basis(const float* __restrict__ x, unsigned short* __restrict__ A2,
                           int i0, int L) {
  int g = blockIdx.x * 256 + threadIdx.x;
  int e0 = g * 8;
  int b = e0 / L;
  int k0 = e0 - b * L;
  const float* xr = x + (size_t)b * 1024 + i0;
  union { unsigned short u[8]; short8 v8; } o;
#pragma unroll
  for (int j = 0; j < 8; ++j) {
    int k = k0 + j;
    int il = (int)(((unsigned)k * 104858u) >> 21);  // k/20, exact for k < 262144
    int gg = k - il * 20;
    float xv = xr[il];
    float d = (xv + 2.0f) * 4.75f - (float)gg;
    o.u[j] = f2bf(__expf(-d * d));
  }
  *reinterpret_cast<short8*>(&A2[(size_t)b * L + k0]) = o.v8;
}

// W [Kp][1024] fp32 -> Bt [1024][Kp] bf16 (transpose+cast), 64x64 LDS tiles.
// grid = (Kp/64) * 16 blocks x 256 thr.
__global__ void prep_wt(const float* __restrict__ W, unsigned short* __restrict__ Bt, int Kp) {
  __shared__ unsigned short tile[64][72];
  int tiles_k = Kp >> 6;
  int bk = blockIdx.x % tiles_k, bn = blockIdx.x / tiles_k;
  int t = threadIdx.x;
  int lr = t >> 4;          // 0..15
  int lc = (t & 15) * 4;    // 0..60
#pragma unroll
  for (int r = 0; r < 4; ++r) {
    int row = r * 16 + lr;
    float4 v = *reinterpret_cast<const float4*>(&W[(size_t)(bk * 64 + row) * 1024 + bn * 64 + lc]);
    tile[row][lc + 0] = f2bf(v.x);
    tile[row][lc + 1] = f2bf(v.y);
    tile[row][lc + 2] = f2bf(v.z);
    tile[row][lc + 3] = f2bf(v.w);
  }
  __syncthreads();
  int nr = t >> 3;          // 0..31
  int kc = (t & 7) * 8;     // 0..56
#pragma unroll
  for (int r = 0; r < 2; ++r) {
    int n = r * 32 + nr;
    union { unsigned short u[8]; short8 v8; } o;
#pragma unroll
    for (int j = 0; j < 8; ++j) o.u[j] = tile[kc + j][n];
    *reinterpret_cast<short8*>(&Bt[(size_t)(bn * 64 + n) * Kp + bk * 64 + kc]) = o.v8;
  }
}

// ---------------- GEMM ----------------
// C[M,N] (+)= A[M,K] @ Bt[N,K]^T, bf16 inputs, fp32 out.
// 128x128x64 tile, 4 waves (each a 64x64 quadrant of 4x4 16x16 frags),
// mfma_f32_16x16x32_bf16, global_load_lds(16B) staging, single LDS buffer
// (explicit dbuf is null at this structure -- m99/m100; residency hides stall).
// grid = NZ*256 blocks; z = wg>>8 selects K-slice [z*Kz, (z+1)*Kz).
// ATOMIC: epilogue atomicAdd (z-partials merge); else plain store.
template <bool ATOMIC>
__global__ __launch_bounds__(256, 4) void gemm_bf16(
    const unsigned short* __restrict__ A, int lda,
    const unsigned short* __restrict__ Bt, int ldb,
    float* __restrict__ C, int Kz) {
  const int tid = threadIdx.x;
  const int wid = tid >> 6, lane = tid & 63;

  // XCD-aware swizzle (nwg % 8 == 0): each XCD gets a contiguous wg chunk
  const int cpx = gridDim.x >> 3;
  const int wg = (blockIdx.x & 7) * cpx + (blockIdx.x >> 3);
  const int mtile = wg & 31;
  const int ntile = (wg >> 5) & 7;
  const int z = wg >> 8;
  const int brow = mtile * 128, bcol = ntile * 128;
  const int kbase = z * Kz;

  __shared__ __align__(16) unsigned short As[128 * 64];
  __shared__ __align__(16) unsigned short Bs[128 * 64];

  // staging: 16 chunks of 1KB each for A and B; wave w owns chunks w*4..w*4+3
  const int srow = wid * 32 + (lane >> 3);  // + c*8
  const int scol = (lane & 7) * 8;
  const unsigned short* aptr = A + (size_t)(brow + srow) * lda + kbase + scol;
  const unsigned short* bptr = Bt + (size_t)(bcol + srow) * ldb + kbase + scol;
  unsigned short* lA = &As[wid * 2048];
  unsigned short* lB = &Bs[wid * 2048];

  const int wr = wid >> 1, wc = wid & 1;
  const int fr = lane & 15;
  const int fk = (lane >> 4) * 8;

  f32x4 acc[4][4] = {};

  for (int kt = 0; kt < Kz; kt += 64) {
#pragma unroll
    for (int c = 0; c < 4; ++c)
      gload_lds16(aptr + (size_t)(c * 8) * lda, lA + c * 512);
#pragma unroll
    for (int c = 0; c < 4; ++c)
      gload_lds16(bptr + (size_t)(c * 8) * ldb, lB + c * 512);
    aptr += 64;
    bptr += 64;
    __syncthreads();  // compiler drains vmcnt(0) before barrier -> tiles ready
#pragma unroll
    for (int ks = 0; ks < 2; ++ks) {
      bf16x8 af[4], bfr[4];
#pragma unroll
      for (int m = 0; m < 4; ++m)
        af[m] = __builtin_bit_cast(
            bf16x8, *reinterpret_cast<const short8*>(
                        &As[(wr * 64 + m * 16 + fr) * 64 + ks * 32 + fk]));
#pragma unroll
      for (int n = 0; n < 4; ++n)
        bfr[n] = __builtin_bit_cast(
            bf16x8, *reinterpret_cast<const short8*>(
                        &Bs[(wc * 64 + n * 16 + fr) * 64 + ks * 32 + fk]));
#pragma unroll
      for (int m = 0; m < 4; ++m)
#pragma unroll
        for (int n = 0; n < 4; ++n)
          acc[m][n] = __builtin_amdgcn_mfma_f32_16x16x32_bf16(af[m], bfr[n], acc[m][n], 0, 0, 0);
    }
    __syncthreads();  // all waves done reading before next stage overwrites
  }

  // C/D layout (m89-verified): col = lane&15, row = (lane>>4)*4 + reg
  const int r0 = brow + wr * 64 + (lane >> 4) * 4;
  const int c0 = bcol + wc * 64 + (lane & 15);
#pragma unroll
  for (int m = 0; m < 4; ++m)
#pragma unroll
    for (int n = 0; n < 4; ++n)
#pragma unroll
      for (int j = 0; j < 4; ++j) {
        size_t idx = (size_t)(r0 + m * 16 + j) * 1024 + (c0 + n * 16);
        float v = acc[m][n][j];
        if (ATOMIC)
          atomicAdd(&C[idx], v);
        else
          C[idx] = v;
      }
}

// ---------------- launcher ----------------

extern "C" void kernel_launch(void* const* d_in, const int* in_sizes, int n_in,
                              void* d_out, int out_size, void* d_ws, size_t ws_size,
                              hipStream_t stream) {
  (void)in_sizes; (void)n_in; (void)out_size;
  const float* x = (const float*)d_in[0];
  const float* Wb = (const float*)d_in[1];
  const float* Ws = (const float*)d_in[2];
  // d_in[3] = mu, folded analytically (mu_g = -2 + g*(4/19))
  float* out = (float*)d_out;
  char* ws = (char*)d_ws;

  // fixed-region layout
  const size_t A1_off = 0;                       //  8,388,608 B
  const size_t W1t_off = 8388608;                //  2,097,152 B
  const size_t dyn_off = W1t_off + 2097152;      // = 10,485,760
  unsigned short* A1  = (unsigned short*)(ws + A1_off);
  unsigned short* W1t = (unsigned short*)(ws + W1t_off);

  // pick npass (spline split) so dynamic buffers fit in ws:
  // per pass: A2 = 4096*CI*20*2 bytes, W2t = CI*20*1024*2 bytes, CI = 1024/npass
  int npass = 16;
  for (int np = 2; np <= 16; np <<= 1) {
    size_t CI = 1024 / np;
    size_t need = dyn_off + 4096ull * CI * 20 * 2 + CI * 20 * 1024 * 2;
    if (need <= ws_size) { npass = np; break; }
  }
  const int CI = 1024 / npass;
  const int Kp = CI * 20;          // K per pass (div by 256 for CI in {64..512})
  const int Kz = Kp / 4;           // per z-slice (npass=2 -> 2560, always /64)
  unsigned short* A2  = (unsigned short*)(ws + dyn_off);
  unsigned short* W2t = (unsigned short*)(ws + dyn_off + 4096ull * CI * 20 * 2);

  // base path: plain-store GEMM initializes every out element
  prep_silu<<<2048, 256, 0, stream>>>(x, A1);
  prep_wt<<<256, 256, 0, stream>>>(Wb, W1t, 1024);
  gemm_bf16<false><<<256, 256, 0, stream>>>(A1, 1024, W1t, 1024, out, 1024);

  // spline path: npass serial passes, each K z-split x4 (grid 1024 = 4 blk/CU),
  // partials merged into out via atomicAdd epilogue
  for (int p = 0; p < npass; ++p) {
    const int nb_basis = 4096 * Kp / 8 / 256;  // exact division
    prep_basis<<<nb_basis, 256, 0, stream>>>(x, A2, p * CI, Kp);
    prep_wt<<<(Kp / 64) * 16, 256, 0, stream>>>(Ws + (size_t)p * Kp * 1024, W2t, Kp);
    gemm_bf16<true><<<1024, 256, 0, stream>>>(A2, Kp, W2t, Kp, out, Kz);
  }
}

// Round 10
// 436.838 us; speedup vs baseline: 1.1552x; 1.0872x over previous
//
#include <hip/hip_runtime.h>
#include <hip/hip_bf16.h>
#include <stdint.h>

// KAN layer = one augmented GEMM:
//   out[4096,1024] = [silu(x) | rbf_basis(x)] @ [W_base ; W_spline]
//   M=4096, N=1024, K=1024+20480=21504, 1.8e11 FLOP -> bf16 MFMA.
// R7 -> R8:
//  (a) LDS XOR chunk-swizzle (T2/G4, both-sides involution): R7 PMC showed
//      SQ_LDS_BANK_CONFLICT = 12 extra cyc per ds_read_b128 -> LDS pipe ~76%
//      of dispatch = critical path. Staging pre-swizzles the GLOBAL column
//      (scol = ((lane&7)^(lane>>3))*8, rule #21) and reads un-swizzle with
//      chunk ^ (row&7). 8 lanes/4-bank group, balanced -> 8-cyc floor.
//  (b) base path folded into pass-0 augmented GEMM (K=1024+CI*20);
//      out zeroed via hipMemsetAsync; ALL gemm epilogues atomicAdd.
// Pipeline:
//   memset(out); for pass p: prep (silu into cols 0..1023 of pass 0 +
//   basis + W^T) -> gemm (grid 1024 = 4 z-slices x 256 tiles, atomic).

typedef short short8 __attribute__((ext_vector_type(8)));
typedef __bf16 bf16x8 __attribute__((ext_vector_type(8)));
typedef float f32x4 __attribute__((ext_vector_type(4)));
typedef unsigned int u32;

__device__ __forceinline__ unsigned short f2bf(float f) {
  __hip_bfloat16 h = __float2bfloat16(f);
  return __builtin_bit_cast(unsigned short, h);
}

__device__ __forceinline__ void gload_lds16(const unsigned short* g, unsigned short* l) {
  // async global->LDS, 16B per lane; LDS dest = wave-uniform base + lane*16
  __builtin_amdgcn_global_load_lds(
      (const __attribute__((address_space(1))) u32*)(const void*)g,
      (__attribute__((address_space(3))) u32*)(void*)l, 16, 0, 0);
}

// ---------------- prep kernels ----------------

// silu(x) -> bf16 into A[row][0..1023] with row stride ld.
// grid 2048x256 exact (4096*1024/8).
__global__ void prep_silu(const float* __restrict__ x, unsigned short* __restrict__ A, int ld) {
  int g = blockIdx.x * 256 + threadIdx.x;
  int row = g >> 7;
  int col = (g & 127) * 8;
  const float4* x4 = reinterpret_cast<const float4*>(x);
  float4 a = x4[g * 2], b = x4[g * 2 + 1];
  float v[8] = {a.x, a.y, a.z, a.w, b.x, b.y, b.z, b.w};
  union { unsigned short u[8]; short8 v8; } o;
#pragma unroll
  for (int j = 0; j < 8; ++j) {
    float s = v[j] / (1.f + __expf(-v[j]));
    o.u[j] = f2bf(s);
  }
  *reinterpret_cast<short8*>(&A[(size_t)row * ld + col]) = o.v8;
}

// RBF basis for i in [i0, i0+CI): A[b][col_off + (i-i0)*20+g] = exp(-d^2),
// d = (x+2)*4.75 - g  (SIGMA = 4/19 -> 1/SIGMA = 4.75 exactly).
// L = CI*20 basis columns; row stride ld; grid covers 4096*L/8 threads exactly.
__global__ void prep_basis(const float* __restrict__ x, unsigned short* __restrict__ A,
                           int i0, int L, int ld, int col_off) {
  int g = blockIdx.x * 256 + threadIdx.x;
  int e0 = g * 8;
  int b = e0 / L;
  int k0 = e0 - b * L;
  const float* xr = x + (size_t)b * 1024 + i0;
  union { unsigned short u[8]; short8 v8; } o;
#pragma unroll
  for (int j = 0; j < 8; ++j) {
    int k = k0 + j;
    int il = (int)(((unsigned)k * 104858u) >> 21);  // k/20, exact for k < 262144
    int gg = k - il * 20;
    float xv = xr[il];
    float d = (xv + 2.0f) * 4.75f - (float)gg;
    o.u[j] = f2bf(__expf(-d * d));
  }
  *reinterpret_cast<short8*>(&A[(size_t)b * ld + col_off + k0]) = o.v8;
}

// W [Kp][1024] fp32 -> Bt[n][k_off + k] bf16 (transpose+cast), 64x64 LDS tiles.
// grid = (Kp/64) * 16 blocks x 256 thr.
__global__ void prep_wt(const float* __restrict__ W, unsigned short* __restrict__ Bt,
                        int Kp, int ldbt, int k_off) {
  __shared__ unsigned short tile[64][72];
  int tiles_k = Kp >> 6;
  int bk = blockIdx.x % tiles_k, bn = blockIdx.x / tiles_k;
  int t = threadIdx.x;
  int lr = t >> 4;          // 0..15
  int lc = (t & 15) * 4;    // 0..60
#pragma unroll
  for (int r = 0; r < 4; ++r) {
    int row = r * 16 + lr;
    float4 v = *reinterpret_cast<const float4*>(&W[(size_t)(bk * 64 + row) * 1024 + bn * 64 + lc]);
    tile[row][lc + 0] = f2bf(v.x);
    tile[row][lc + 1] = f2bf(v.y);
    tile[row][lc + 2] = f2bf(v.z);
    tile[row][lc + 3] = f2bf(v.w);
  }
  __syncthreads();
  int nr = t >> 3;          // 0..31
  int kc = (t & 7) * 8;     // 0..56
#pragma unroll
  for (int r = 0; r < 2; ++r) {
    int n = r * 32 + nr;
    union { unsigned short u[8]; short8 v8; } o;
#pragma unroll
    for (int j = 0; j < 8; ++j) o.u[j] = tile[kc + j][n];
    *reinterpret_cast<short8*>(&Bt[(size_t)(bn * 64 + n) * ldbt + k_off + bk * 64 + kc]) = o.v8;
  }
}

// ---------------- GEMM ----------------
// C[M,N] += A[M,K] @ Bt[N,K]^T, bf16 inputs, fp32 atomic out.
// 128x128x64 tile, 4 waves, mfma_f32_16x16x32_bf16, global_load_lds(16B).
// LDS layout XOR-swizzled at 16B-chunk granularity: linear slot (row, ch)
// holds global chunk (ch ^ (row&7)). Staging keeps gload_lds dest linear and
// pre-swizzles the global source column per lane (rule #21: involution on
// both sides). Reads: chunkpos = orig_chunk ^ (row&7) -> 8 lanes per 4-bank
// group, balanced (was 16 -> 2x LDS time).
// grid = 4z * 256 tiles; z = wg>>8 selects K-slice [z*Kz,(z+1)*Kz).
__global__ __launch_bounds__(256, 4) void gemm_bf16(
    const unsigned short* __restrict__ A, int lda,
    const unsigned short* __restrict__ Bt, int ldb,
    float* __restrict__ C, int Kz) {
  const int tid = threadIdx.x;
  const int wid = tid >> 6, lane = tid & 63;

  // XCD-aware swizzle (nwg % 8 == 0): each XCD gets a contiguous wg chunk
  const int cpx = gridDim.x >> 3;
  const int wg = (blockIdx.x & 7) * cpx + (blockIdx.x >> 3);
  const int mtile = wg & 31;
  const int ntile = (wg >> 5) & 7;
  const int z = wg >> 8;
  const int brow = mtile * 128, bcol = ntile * 128;
  const int kbase = z * Kz;

  __shared__ __align__(16) unsigned short As[128 * 64];
  __shared__ __align__(16) unsigned short Bs[128 * 64];

  // staging: wave w owns 1KB chunks w*4..w*4+3 of each tile.
  // lane l -> LDS row (l>>3), dest chunk (l&7); global col chunk pre-swizzled:
  const int srow = wid * 32 + (lane >> 3);                     // + c*8
  const int scol = ((lane & 7) ^ (lane >> 3)) * 8;             // involution
  const unsigned short* aptr = A + (size_t)(brow + srow) * lda + kbase + scol;
  const unsigned short* bptr = Bt + (size_t)(bcol + srow) * ldb + kbase + scol;
  unsigned short* lA = &As[wid * 2048];
  unsigned short* lB = &Bs[wid * 2048];

  const int wr = wid >> 1, wc = wid & 1;
  const int fr = lane & 15;
  const int fg = lane >> 4;          // 0..3 (16B chunk within ks half)

  f32x4 acc[4][4] = {};

  for (int kt = 0; kt < Kz; kt += 64) {
#pragma unroll
    for (int c = 0; c < 4; ++c)
      gload_lds16(aptr + (size_t)(c * 8) * lda, lA + c * 512);
#pragma unroll
    for (int c = 0; c < 4; ++c)
      gload_lds16(bptr + (size_t)(c * 8) * ldb, lB + c * 512);
    aptr += 64;
    bptr += 64;
    __syncthreads();  // compiler drains vmcnt(0) before barrier -> tiles ready
#pragma unroll
    for (int ks = 0; ks < 2; ++ks) {
      bf16x8 af[4], bfr[4];
#pragma unroll
      for (int m = 0; m < 4; ++m) {
        int row = wr * 64 + m * 16 + fr;
        int cp = ((ks * 4 + fg) ^ (fr & 7)) * 8;   // un-swizzle
        af[m] = __builtin_bit_cast(
            bf16x8, *reinterpret_cast<const short8*>(&As[row * 64 + cp]));
      }
#pragma unroll
      for (int n = 0; n < 4; ++n) {
        int row = wc * 64 + n * 16 + fr;
        int cp = ((ks * 4 + fg) ^ (fr & 7)) * 8;
        bfr[n] = __builtin_bit_cast(
            bf16x8, *reinterpret_cast<const short8*>(&Bs[row * 64 + cp]));
      }
#pragma unroll
      for (int m = 0; m < 4; ++m)
#pragma unroll
        for (int n = 0; n < 4; ++n)
          acc[m][n] = __builtin_amdgcn_mfma_f32_16x16x32_bf16(af[m], bfr[n], acc[m][n], 0, 0, 0);
    }
    __syncthreads();  // all waves done reading before next stage overwrites
  }

  // C/D layout (m89-verified): col = lane&15, row = (lane>>4)*4 + reg
  const int r0 = brow + wr * 64 + (lane >> 4) * 4;
  const int c0 = bcol + wc * 64 + (lane & 15);
#pragma unroll
  for (int m = 0; m < 4; ++m)
#pragma unroll
    for (int n = 0; n < 4; ++n)
#pragma unroll
      for (int j = 0; j < 4; ++j) {
        size_t idx = (size_t)(r0 + m * 16 + j) * 1024 + (c0 + n * 16);
        atomicAdd(&C[idx], acc[m][n][j]);
      }
}

// ---------------- launcher ----------------

extern "C" void kernel_launch(void* const* d_in, const int* in_sizes, int n_in,
                              void* d_out, int out_size, void* d_ws, size_t ws_size,
                              hipStream_t stream) {
  (void)in_sizes; (void)n_in; (void)out_size;
  const float* x = (const float*)d_in[0];
  const float* Wb = (const float*)d_in[1];
  const float* Ws = (const float*)d_in[2];
  // d_in[3] = mu, folded analytically (mu_g = -2 + g*(4/19))
  float* out = (float*)d_out;
  char* ws = (char*)d_ws;

  // pick npass (spline split) so buffers fit in ws. Pass 0 is augmented
  // with the base path: K0 = 1024 + CI*20 (largest pass sizes the buffers).
  int npass = 16;
  for (int np = 2; np <= 16; np <<= 1) {
    size_t K0 = 1024 + (1024 / np) * 20;
    size_t need = 4096ull * K0 * 2 + 1024ull * K0 * 2;
    if (need <= ws_size) { npass = np; break; }
  }
  const int CI = 1024 / npass;
  const int K0 = 1024 + CI * 20;   // pass-0 K (augmented)
  const int Ksp = CI * 20;         // pass >=1 K
  unsigned short* A2  = (unsigned short*)ws;
  unsigned short* W2t = (unsigned short*)(ws + 4096ull * K0 * 2);

  // all GEMM epilogues are atomicAdd -> zero out first (stream-ordered,
  // graph-capture legal)
  hipMemsetAsync(out, 0, 4096ull * 1024 * 4, stream);

  for (int p = 0; p < npass; ++p) {
    const int Kfull = (p == 0) ? K0 : Ksp;
    const int col_off = (p == 0) ? 1024 : 0;
    if (p == 0) {
      prep_silu<<<2048, 256, 0, stream>>>(x, A2, Kfull);
      prep_wt<<<256, 256, 0, stream>>>(Wb, W2t, 1024, Kfull, 0);
    }
    prep_basis<<<4096 * Ksp / 8 / 256, 256, 0, stream>>>(x, A2, p * CI, Ksp, Kfull, col_off);
    prep_wt<<<(Ksp / 64) * 16, 256, 0, stream>>>(Ws + (size_t)p * Ksp * 1024, W2t, Ksp, Kfull, col_off);
    gemm_bf16<<<1024, 256, 0, stream>>>(A2, Kfull, W2t, Kfull, out, Kfull / 4);
  }
}